// Round 6
// baseline (1497.096 us; speedup 1.0000x reference)
//
#include <hip/hip_runtime.h>

#define NN 100000
#define MPAD 100096
#define NT_M 782

typedef unsigned short u16;
typedef _Float16 f16x8 __attribute__((ext_vector_type(8)));
typedef __attribute__((ext_vector_type(4))) float f32x4;

__device__ __forceinline__ u16 f2h(float f){
  union { _Float16 h; u16 u; } v; v.h=(_Float16)f; return v.u;
}
__device__ __forceinline__ float h2f(u16 u){
  union { u16 u; _Float16 h; } v; v.u=u; return (float)v.h;
}
__device__ __forceinline__ void gload16(const void* g, void* l){
  __builtin_amdgcn_global_load_lds((const __attribute__((address_space(1))) void*)g,
                                   (__attribute__((address_space(3))) void*)l, 16, 0, 0);
}
__device__ __forceinline__ void lds_fence(){
  asm volatile("s_waitcnt lgkmcnt(0)" ::: "memory");
  __builtin_amdgcn_wave_barrier();
}

// ---------------- fp16 GEMM: C[m,n] = sum_k A[m,k]*B[n,k], BK=64, 128x128 tile
// A split into up to 3 row-major chunks of CW cols each (a0,a1,a2), chunk = (kt*64)/CW.
// EPI 0: store fp16 to cout. EPI 1: out=(acc+tvec[col])*rnorm[row] f32. EPI 2: y2 f32 + col stats.
template<int EPI>
__global__ __launch_bounds__(256) void k_gemm(
  const u16* __restrict__ a0, const u16* __restrict__ a1, const u16* __restrict__ a2,
  const u16* __restrict__ bmat, u16* __restrict__ cout,
  float* __restrict__ outf, const float* __restrict__ tvec,
  const float* __restrict__ rnorm, float* __restrict__ colstats,
  int CW, int Bstride, int KT)
{
  __shared__ u16 lds[2][2][8192];   // [buf][A,B][128 rows x 64 cols fp16]
  __shared__ float cstat[256];
  const int tid=threadIdx.x, lane=tid&63, wid=tid>>6;
  const int wr=wid>>1, wc=wid&1;
  const long m0=(long)blockIdx.x*128;
  const int n0=blockIdx.y*128;
  f32x4 acc[4][4]={};
  if(EPI==2) cstat[tid]=0.f;

  auto stageT=[&](u16* L, const u16* G, long rs){
    #pragma unroll
    for(int i=0;i<4;i++){
      int idx=i*256+tid;
      int row=idx>>3, slot=idx&7;
      int gc=(slot^(row&7))*8;            // inverse-swizzle on the GLOBAL side
      gload16(G+(long)row*rs+gc, L+idx*8);
    }
  };
  auto stage=[&](int buf,int kt){
    int kg=kt*64;
    int chn=kg/CW;
    int kc=kg-chn*CW;
    const u16* Ab = (chn==0)?a0:((chn==1)?a1:a2);
    stageT(lds[buf][0], Ab+m0*CW+kc, CW);
    stageT(lds[buf][1], bmat+(long)n0*Bstride+kg, Bstride);
  };
  stage(0,0);
  __syncthreads();
  int buf=0;
  for(int kt=0;kt<KT;kt++){
    if(kt+1<KT) stage(buf^1,kt+1);
    const u16* LA=lds[buf][0]; const u16* LB=lds[buf][1];
    #pragma unroll
    for(int kk=0;kk<2;kk++){
      f16x8 av[4], bv[4];
      #pragma unroll
      for(int mf=0;mf<4;mf++){
        int r=wr*64+mf*16+(lane&15);
        av[mf]=*(const f16x8*)&LA[r*64 + (((kk*4+(lane>>4))^(r&7))*8)];
      }
      #pragma unroll
      for(int nf=0;nf<4;nf++){
        int r=wc*64+nf*16+(lane&15);
        bv[nf]=*(const f16x8*)&LB[r*64 + (((kk*4+(lane>>4))^(r&7))*8)];
      }
      #pragma unroll
      for(int mf=0;mf<4;mf++){
        #pragma unroll
        for(int nf=0;nf<4;nf++)
          acc[mf][nf]=__builtin_amdgcn_mfma_f32_16x16x32_f16(av[mf],bv[nf],acc[mf][nf],0,0,0);
      }
    }
    __syncthreads();
    buf^=1;
  }
  float csum[4]={0,0,0,0}, csq[4]={0,0,0,0};
  #pragma unroll
  for(int mf=0;mf<4;mf++){
    #pragma unroll
    for(int j=0;j<4;j++){
      long row=m0+wr*64+mf*16+((lane>>4)*4)+j;
      if(row<NN){
        #pragma unroll
        for(int nf=0;nf<4;nf++){
          int col=n0+wc*64+nf*16+(lane&15);
          float v=acc[mf][nf][j];
          if(EPI==1) outf[row*256+col]=(v+tvec[col])*rnorm[row];
          else if(EPI==2){ outf[row*256+col]=v; csum[nf]+=v; csq[nf]+=v*v; }
          else cout[row*256+col]=f2h(v);
        }
      }
    }
  }
  if(EPI==2){
    #pragma unroll
    for(int nf=0;nf<4;nf++){
      int lc=wc*64+nf*16+(lane&15);
      atomicAdd(&cstat[lc],csum[nf]);
      atomicAdd(&cstat[128+lc],csq[nf]);
    }
    __syncthreads();
    if(tid<128){
      atomicAdd(&colstats[n0+tid],cstat[tid]);
      atomicAdd(&colstats[256+n0+tid],cstat[128+tid]);
    }
  }
}

// ---------------- x patch moments
__global__ __launch_bounds__(256) void k_xmom(const float* __restrict__ x, float* __restrict__ stats){
  int t=blockIdx.x*blockDim.x+threadIdx.x, stride=gridDim.x*blockDim.x;
  int lane=threadIdx.x&63;
  float m[5]={0,0,0,0,0};
  float c[15]={0,0,0,0,0,0,0,0,0,0,0,0,0,0,0};
  for(int n=t;n<NN;n+=stride){
    float xr[60];
    #pragma unroll
    for(int i=0;i<15;i++){
      float4 v=*(const float4*)&x[(long)n*60+i*4];
      xr[i*4]=v.x; xr[i*4+1]=v.y; xr[i*4+2]=v.z; xr[i*4+3]=v.w;
    }
    #pragma unroll
    for(int p=0;p<12;p++){
      float vv[5]={xr[5*p],xr[5*p+1],xr[5*p+2],xr[5*p+3],xr[5*p+4]};
      #pragma unroll
      for(int k=0;k<5;k++) m[k]+=vv[k];
      int idx=0;
      #pragma unroll
      for(int k=0;k<5;k++){
        #pragma unroll
        for(int k2=k;k2<5;k2++){ c[idx]+=vv[k]*vv[k2]; idx++; }
      }
    }
  }
  float vals[20];
  #pragma unroll
  for(int i=0;i<5;i++) vals[i]=m[i];
  #pragma unroll
  for(int i=0;i<15;i++) vals[5+i]=c[i];
  #pragma unroll
  for(int i=0;i<20;i++){
    float v=vals[i];
    #pragma unroll
    for(int off=32;off;off>>=1) v+=__shfl_xor(v,off);
    if(lane==0) atomicAdd(&stats[i],v);
  }
}

__global__ void k_fin1(const float* __restrict__ stats, const float* __restrict__ w1,
                       const float* __restrict__ b1, const float* __restrict__ g,
                       const float* __restrict__ bt, float* __restrict__ a1c1){
  int c=threadIdx.x;
  if(c>=32) return;
  const float inv=1.0f/(NN*12.0f);
  float mu[5];
  for(int k=0;k<5;k++) mu[k]=stats[k]*inv;
  float C[5][5];
  int idx=5;
  for(int k=0;k<5;k++) for(int k2=k;k2<5;k2++){ float v=stats[idx++]*inv; C[k][k2]=v; C[k2][k]=v; }
  float wv[5];
  for(int k=0;k<5;k++) wv[k]=w1[c*5+k];
  float bb=b1[c];
  float mean=bb, e2=bb*bb;
  for(int k=0;k<5;k++){ mean+=wv[k]*mu[k]; e2+=2.f*bb*wv[k]*mu[k]; }
  for(int k=0;k<5;k++) for(int k2=0;k2<5;k2++) e2+=wv[k]*wv[k2]*C[k][k2];
  float var=e2-mean*mean;
  float a=g[c]*rsqrtf(var+1e-5f);
  a1c1[c]=a; a1c1[32+c]=bt[c]-mean*a;
}

// transform vectors: vL[h][k] = sum_c fc[h*128+c, k] * a[h,c]
__global__ void k_prep(const float* __restrict__ fc1, const float* __restrict__ fc2,
                       const float* __restrict__ a1l, const float* __restrict__ a1r,
                       const float* __restrict__ a2l, const float* __restrict__ a2r,
                       float* __restrict__ vprep){
  int k=threadIdx.x;
  float acc[8]={0,0,0,0,0,0,0,0};
  for(int r=0;r<256;r++){
    int h=r>>7, c=r&127;
    float f1=fc1[r*256+k], f2=fc2[r*256+k];
    acc[0+h]+=f1*a1l[h*128+c];
    acc[2+h]+=f1*a1r[h*128+c];
    acc[4+h]+=f2*a2l[h*128+c];
    acc[6+h]+=f2*a2r[h*128+c];
  }
  #pragma unroll
  for(int v=0;v<8;v++) vprep[v*256+k]=acc[v];
}

// dense conv2 weight: wd[c2*4+p][ci*12+3p+k] = w2[c2,ci,k], else 0  (fp16)
__global__ void k_w2d(const float* __restrict__ w2, u16* __restrict__ wd){
  int j=threadIdx.x;
  if(j>=256) return;
  int c2=j>>2, p=j&3;
  for(int t=0;t<384;t++) wd[j*384+t]=0;
  for(int ci=0;ci<32;ci++)
    for(int k=0;k<3;k++)
      wd[j*384 + ci*12 + 3*p + k]=f2h(w2[(c2*32+ci)*3+k]);
}

// conv1 + bn1 + relu -> z1 fp16 [MPAD x 384], layout col = ci*12 + pos
__global__ __launch_bounds__(256) void k_z1(const float* __restrict__ x,
  const float* __restrict__ w1, const float* __restrict__ b1,
  const float* __restrict__ a1c1, u16* __restrict__ z1)
{
  __shared__ float w1s[160], a1s[32], c1s[32], b1s[32];
  __shared__ float xs[4][64];
  int tid=threadIdx.x, lane=tid&63, w=tid>>6;
  if(tid<160) w1s[tid]=w1[tid];
  if(tid<32){ a1s[tid]=a1c1[tid]; c1s[tid]=a1c1[32+tid]; b1s[tid]=b1[tid]; }
  __syncthreads();
  int gw=blockIdx.x*4+w, nw=gridDim.x*4;
  int c=lane>>1, pb=(lane&1)*6;
  float av=a1s[c], cv=c1s[c], bb=b1s[c];
  float wv[5];
  #pragma unroll
  for(int k=0;k<5;k++) wv[k]=w1s[c*5+k];
  for(int n=gw;n<NN;n+=nw){
    if(lane<60) xs[w][lane]=x[(long)n*60+lane];
    lds_fence();
    ushort2 zz[3];
    #pragma unroll
    for(int i=0;i<6;i++){
      int p=pb+i;
      float y=bb;
      #pragma unroll
      for(int k=0;k<5;k++) y+=xs[w][5*p+k]*wv[k];
      u16 h=f2h(fmaxf(y*av+cv,0.f));
      if(i&1) zz[i>>1].y=h; else zz[i>>1].x=h;
    }
    long base=(long)n*384 + c*12 + pb;
    *(ushort2*)&z1[base]  =zz[0];
    *(ushort2*)&z1[base+2]=zz[1];
    *(ushort2*)&z1[base+4]=zz[2];
    lds_fence();
  }
}

// per-column stats -> per-channel bn2 affine
__global__ void k_fin2(const float* __restrict__ cs, const float* __restrict__ g,
                       const float* __restrict__ bt, float* __restrict__ a2c2){
  int c=threadIdx.x;
  if(c>=64) return;
  float s=cs[4*c]+cs[4*c+1]+cs[4*c+2]+cs[4*c+3];
  float q=cs[256+4*c]+cs[256+4*c+1]+cs[256+4*c+2]+cs[256+4*c+3];
  const float inv=1.0f/(NN*4.0f);
  float mean=s*inv;
  float var=q*inv-mean*mean;
  float a=g[c]*rsqrtf(var+1e-5f);
  a2c2[c]=a; a2c2[64+c]=bt[c]-mean*a;
}

// apply bn2+relu to y2 -> h fp16; + layer-1 el/er epilogue (fp32)
__global__ __launch_bounds__(256) void k_happ(const float* __restrict__ y2,
  const float* __restrict__ a2c2, const float* __restrict__ vprep,
  u16* __restrict__ h, float* __restrict__ elv, float* __restrict__ erv)
{
  int lane=threadIdx.x&63;
  int gw=blockIdx.x*4+(threadIdx.x>>6), nw=gridDim.x*4;
  float a2=a2c2[lane], c2v=a2c2[64+lane];   // channel == lane (cols lane*4..lane*4+3)
  int cb=lane*4;
  float4 vl0=*(const float4*)&vprep[cb];
  float4 vl1=*(const float4*)&vprep[256+cb];
  float4 vr0=*(const float4*)&vprep[512+cb];
  float4 vr1=*(const float4*)&vprep[768+cb];
  for(int n=gw;n<NN;n+=nw){
    float4 y=*(const float4*)&y2[(long)n*256+cb];
    float o0=fmaxf(y.x*a2+c2v,0.f), o1=fmaxf(y.y*a2+c2v,0.f);
    float o2=fmaxf(y.z*a2+c2v,0.f), o3=fmaxf(y.w*a2+c2v,0.f);
    ushort4 o; o.x=f2h(o0); o.y=f2h(o1); o.z=f2h(o2); o.w=f2h(o3);
    *(ushort4*)&h[(long)n*256+cb]=o;
    float pl0=o0*vl0.x+o1*vl0.y+o2*vl0.z+o3*vl0.w;
    float pl1=o0*vl1.x+o1*vl1.y+o2*vl1.z+o3*vl1.w;
    float pr0=o0*vr0.x+o1*vr0.y+o2*vr0.z+o3*vr0.w;
    float pr1=o0*vr1.x+o1*vr1.y+o2*vr1.z+o3*vr1.w;
    #pragma unroll
    for(int off=32;off;off>>=1){
      pl0+=__shfl_xor(pl0,off); pl1+=__shfl_xor(pl1,off);
      pr0+=__shfl_xor(pr0,off); pr1+=__shfl_xor(pr1,off);
    }
    if(lane==0){ elv[2*n]=pl0; elv[2*n+1]=pl1; erv[2*n]=pr0; erv[2*n+1]=pr1; }
  }
}

// f32 -> fp16
__global__ void k_cvth(const float* __restrict__ in, u16* __restrict__ out, int n){
  int i=blockIdx.x*blockDim.x+threadIdx.x;
  if(i<n) out[i]=f2h(in[i]);
}

// fold dbn scale into l2-normalized cos_W rows (fp16); t[r] = sum_k c_k * Wn_k / ||Wn||
__global__ __launch_bounds__(256) void k_wfold(const float* __restrict__ cw, const float* __restrict__ ab,
  u16* __restrict__ wh, float* __restrict__ tvec)
{
  int lane=threadIdx.x&63;
  int r=blockIdx.x*4+(threadIdx.x>>6);
  if(r>=256) return;
  float v[12]; float ss=0.f, tn=0.f;
  #pragma unroll
  for(int i=0;i<12;i++){
    int col=i*64+lane;
    v[i]=cw[r*768+col];
    ss+=v[i]*v[i];
    tn+=v[i]*ab[768+col];
  }
  #pragma unroll
  for(int off=32;off;off>>=1){ ss+=__shfl_xor(ss,off); tn+=__shfl_xor(tn,off); }
  float sc=1.0f/fmaxf(sqrtf(ss),1e-12f);
  #pragma unroll
  for(int i=0;i<12;i++){
    int col=i*64+lane;
    wh[r*768+col]=f2h(v[i]*sc*ab[col]);
  }
  if(lane==0) tvec[r]=tn*sc;
}

// per-node softmax over 16 contiguous edges -> alpha[n*32 + 2j + head]
__global__ __launch_bounds__(256) void k_alpha(const float* __restrict__ el, const float* __restrict__ er,
  const int* __restrict__ srcv, float* __restrict__ alpha)
{
  int n=blockIdx.x*blockDim.x+threadIdx.x;
  if(n>=NN) return;
  int sidx[16];
  #pragma unroll
  for(int j=0;j<16;j+=4){
    int4 v=*(const int4*)&srcv[n*16+j];
    sidx[j]=v.x; sidx[j+1]=v.y; sidx[j+2]=v.z; sidx[j+3]=v.w;
  }
  float er0=er[2*n], er1=er[2*n+1];
  float e0[16], e1[16];
  float mx0=-1e30f, mx1=-1e30f;
  #pragma unroll
  for(int j=0;j<16;j++){
    float a=el[2*sidx[j]]+er0;
    float bb=el[2*sidx[j]+1]+er1;
    a = a>0.f? a : 0.2f*a;
    bb = bb>0.f? bb : 0.2f*bb;
    e0[j]=a; e1[j]=bb;
    mx0=fmaxf(mx0,a); mx1=fmaxf(mx1,bb);
  }
  float d0=0.f,d1=0.f;
  #pragma unroll
  for(int j=0;j<16;j++){
    e0[j]=__expf(e0[j]-mx0); d0+=e0[j];
    e1[j]=__expf(e1[j]-mx1); d1+=e1[j];
  }
  float r0=1.f/fmaxf(d0,1e-12f), r1=1.f/fmaxf(d1,1e-12f);
  #pragma unroll
  for(int j=0;j<16;j++){
    float2 o; o.x=e0[j]*r0; o.y=e1[j]*r1;
    ((float2*)alpha)[(long)n*16+j]=o;
  }
}

template<int ACT> __device__ __forceinline__ float actf(float g);
template<> __device__ __forceinline__ float actf<1>(float g){
  float t=tanhf(g);
  float ls=fminf(g,0.f)-log1pf(__expf(-fabsf(g)));
  return fmaxf(g,0.f)+t+ls;
}
template<> __device__ __forceinline__ float actf<2>(float g){ return tanhf(g); }
template<> __device__ __forceinline__ float actf<3>(float g){ return fmaxf(g,0.f); }

// gather-aggregate with precomputed alpha (fp16 feat); fp16 h store + dbn stats; optional next el/er
template<int ACT,int WELR>
__global__ __launch_bounds__(256) void k_aggr(const u16* __restrict__ fH,
  const float* __restrict__ alpha, const int* __restrict__ srcv, const float* __restrict__ bias,
  u16* __restrict__ hH, float* __restrict__ dbn_raw, int col_base,
  const float* __restrict__ vnext, float* __restrict__ elo, float* __restrict__ ero)
{
  __shared__ float bsum[256], bsq[256];
  int tid=threadIdx.x, lane=tid&63;
  bsum[tid]=0.f; bsq[tid]=0.f;
  __syncthreads();
  int gw=blockIdx.x*4+(tid>>6), nw=gridDim.x*4;
  int head=lane>>5, cb=lane*4;
  float4 b4=*(const float4*)&bias[cb];
  float4 vl0={0,0,0,0},vl1={0,0,0,0},vr0={0,0,0,0},vr1={0,0,0,0};
  if(WELR){
    vl0=*(const float4*)&vnext[cb];
    vl1=*(const float4*)&vnext[256+cb];
    vr0=*(const float4*)&vnext[512+cb];
    vr1=*(const float4*)&vnext[768+cb];
  }
  float s[4]={0,0,0,0}, q[4]={0,0,0,0};
  for(int n=gw;n<NN;n+=nw){
    int sidx[16];
    #pragma unroll
    for(int j=0;j<16;j+=4){
      int4 v=*(const int4*)&srcv[n*16+j];
      sidx[j]=v.x; sidx[j+1]=v.y; sidx[j+2]=v.z; sidx[j+3]=v.w;
    }
    float a0=b4.x,a1=b4.y,a2=b4.z,a3=b4.w;
    #pragma unroll
    for(int j=0;j<16;j++){
      float2 aw2=((const float2*)alpha)[(long)n*16+j];
      float aw = head? aw2.y : aw2.x;
      ushort4 f=*(const ushort4*)&fH[(long)sidx[j]*256+cb];
      a0+=aw*h2f(f.x); a1+=aw*h2f(f.y);
      a2+=aw*h2f(f.z); a3+=aw*h2f(f.w);
    }
    float h0=actf<ACT>(a0), h1=actf<ACT>(a1), h2=actf<ACT>(a2), h3=actf<ACT>(a3);
    ushort4 o; o.x=f2h(h0); o.y=f2h(h1); o.z=f2h(h2); o.w=f2h(h3);
    *(ushort4*)&hH[(long)n*256+cb]=o;
    s[0]+=h0; s[1]+=h1; s[2]+=h2; s[3]+=h3;
    q[0]+=h0*h0; q[1]+=h1*h1; q[2]+=h2*h2; q[3]+=h3*h3;
    if(WELR){
      float pl0=h0*vl0.x+h1*vl0.y+h2*vl0.z+h3*vl0.w;
      float pl1=h0*vl1.x+h1*vl1.y+h2*vl1.z+h3*vl1.w;
      float pr0=h0*vr0.x+h1*vr0.y+h2*vr0.z+h3*vr0.w;
      float pr1=h0*vr1.x+h1*vr1.y+h2*vr1.z+h3*vr1.w;
      #pragma unroll
      for(int off2=32;off2;off2>>=1){
        pl0+=__shfl_xor(pl0,off2); pl1+=__shfl_xor(pl1,off2);
        pr0+=__shfl_xor(pr0,off2); pr1+=__shfl_xor(pr1,off2);
      }
      if(lane==0){ elo[2*n]=pl0; elo[2*n+1]=pl1; ero[2*n]=pr0; ero[2*n+1]=pr1; }
    }
  }
  #pragma unroll
  for(int i=0;i<4;i++){ atomicAdd(&bsum[cb+i], s[i]); atomicAdd(&bsq[cb+i], q[i]); }
  __syncthreads();
  atomicAdd(&dbn_raw[col_base+tid], bsum[tid]);
  atomicAdd(&dbn_raw[768+col_base+tid], bsq[tid]);
}

__global__ void k_dbnfin(const float* __restrict__ raw, const float* __restrict__ g,
                         const float* __restrict__ b, float* __restrict__ ab){
  int c=blockIdx.x*blockDim.x+threadIdx.x;
  if(c<768){
    float mean=raw[c]*(1.0f/NN);
    float var=raw[768+c]*(1.0f/NN)-mean*mean;
    float a=g[c]*rsqrtf(var+1e-5f);
    ab[c]=a; ab[768+c]=b[c]-mean*a;
  }
}

// rnorm[n] = 4.6 / || dbn(h1|h2|h3) ||  from fp16 h
__global__ __launch_bounds__(256) void k_rnorm(
  const u16* __restrict__ h1h, const u16* __restrict__ h2h, const u16* __restrict__ h3h,
  const float* __restrict__ ab, float* __restrict__ rn)
{
  int lane=threadIdx.x&63;
  int gw=blockIdx.x*4+(threadIdx.x>>6), nw=gridDim.x*4;
  int cb=lane*4;
  float av[12], cv[12];
  #pragma unroll
  for(int s=0;s<3;s++){
    #pragma unroll
    for(int i=0;i<4;i++){ av[s*4+i]=ab[s*256+cb+i]; cv[s*4+i]=ab[768+s*256+cb+i]; }
  }
  for(int n=gw;n<NN;n+=nw){
    float ss=0.f;
    const u16* hh[3]={h1h,h2h,h3h};
    #pragma unroll
    for(int s=0;s<3;s++){
      ushort4 a4=*(const ushort4*)&hh[s][(long)n*256+cb];
      float o0=h2f(a4.x)*av[s*4+0]+cv[s*4+0];
      float o1=h2f(a4.y)*av[s*4+1]+cv[s*4+1];
      float o2=h2f(a4.z)*av[s*4+2]+cv[s*4+2];
      float o3=h2f(a4.w)*av[s*4+3]+cv[s*4+3];
      ss+=o0*o0+o1*o1+o2*o2+o3*o3;
    }
    #pragma unroll
    for(int off=32;off;off>>=1) ss+=__shfl_xor(ss,off);
    if(lane==0) rn[n]=4.6f/fmaxf(sqrtf(ss),1e-12f);
  }
}

extern "C" void kernel_launch(void* const* d_in, const int* in_sizes, int n_in,
                              void* d_out, int out_size, void* d_ws, size_t ws_size,
                              hipStream_t stream)
{
  (void)in_sizes; (void)n_in; (void)out_size; (void)ws_size;
  const float* x   =(const float*)d_in[0];
  const int*   src =(const int*)d_in[1];
  const float* w1  =(const float*)d_in[3];
  const float* b1  =(const float*)d_in[4];
  const float* bn1g=(const float*)d_in[5];
  const float* bn1b=(const float*)d_in[6];
  const float* w2  =(const float*)d_in[7];
  const float* b2  =(const float*)d_in[8];
  const float* bn2g=(const float*)d_in[9];
  const float* bn2b=(const float*)d_in[10];
  const float* fc1 =(const float*)d_in[11];
  const float* a1l =(const float*)d_in[12];
  const float* a1r =(const float*)d_in[13];
  const float* bias1=(const float*)d_in[14];
  const float* fc2 =(const float*)d_in[15];
  const float* a2l =(const float*)d_in[16];
  const float* a2r =(const float*)d_in[17];
  const float* bias2=(const float*)d_in[18];
  const float* dbng=(const float*)d_in[19];
  const float* dbnb=(const float*)d_in[20];
  const float* cw  =(const float*)d_in[21];

  char* ws=(char*)d_ws;
  size_t off=0;
  auto take=[&](size_t bytes)->char*{ char* p=ws+off; off=(off+bytes+255)&~(size_t)255; return p; };
  float* stats =(float*)take(4096*4);
  float* params=(float*)take(4096*4);
  float* el    =(float*)take((size_t)MPAD*2*4);
  float* er    =(float*)take((size_t)MPAD*2*4);
  float* rnorm =(float*)take((size_t)MPAD*4);
  float* tvec  =(float*)take(256*4);
  float* alpha =(float*)take((size_t)NN*32*4);
  u16* fc1h=(u16*)take((size_t)65536*2);
  u16* fc2h=(u16*)take((size_t)65536*2);
  u16* wfh =(u16*)take((size_t)196608*2);
  u16* w2d =(u16*)take((size_t)98304*2);
  u16* z1  =(u16*)take((size_t)MPAD*384*2);
  float* y2 =(float*)take((size_t)MPAD*256*4);
  const size_t FB=(size_t)MPAD*256*2;
  u16* h0H  =(u16*)take(FB);   // conv h; later h3
  u16* h1H  =(u16*)take(FB);
  u16* h2H  =(u16*)take(FB);
  u16* featH=(u16*)d_out;      // fp16 feat lives in d_out until the final GEMM

  float* xmom   =stats;        // 20
  float* stats2 =stats+64;     // 512 (256 col sums + 256 col sq)
  float* dbn_raw=stats+1024;   // 1536
  float* a1c1   =params;       // 64
  float* a2c2   =params+64;    // 128
  float* dbn_ab =params+256;   // 1536
  float* vprep  =params+2048;  // 2048 (8 x 256)

  hipMemsetAsync(stats,0,4096*4,stream);
  k_cvth<<<dim3(256),dim3(256),0,stream>>>(fc1,fc1h,65536);
  k_cvth<<<dim3(256),dim3(256),0,stream>>>(fc2,fc2h,65536);
  k_prep<<<dim3(1),dim3(256),0,stream>>>(fc1,fc2,a1l,a1r,a2l,a2r,vprep);
  k_w2d<<<dim3(1),dim3(256),0,stream>>>(w2,w2d);
  k_xmom<<<dim3(128),dim3(256),0,stream>>>(x,xmom);
  k_fin1<<<dim3(1),dim3(64),0,stream>>>(xmom,w1,b1,bn1g,bn1b,a1c1);
  k_z1<<<dim3(1024),dim3(256),0,stream>>>(x,w1,b1,a1c1,z1);

  dim3 gg(NT_M,2);
  // conv2 as GEMM: y2 = z1 @ w2d^T, + per-column stats
  k_gemm<2><<<gg,dim3(256),0,stream>>>(z1,z1,z1,w2d,(u16*)nullptr,y2,
                                       (float*)nullptr,(float*)nullptr,stats2,384,384,6);
  k_fin2<<<dim3(1),dim3(64),0,stream>>>(stats2,bn2g,bn2b,a2c2);
  k_happ<<<dim3(2048),dim3(256),0,stream>>>(y2,a2c2,vprep,h0H,el,er);

  // GAT layer 1
  k_gemm<0><<<gg,dim3(256),0,stream>>>(h0H,h0H,h0H,fc1h,featH,(float*)nullptr,
                                       (float*)nullptr,(float*)nullptr,(float*)nullptr,256,256,4);
  k_alpha<<<dim3(391),dim3(256),0,stream>>>(el,er,src,alpha);
  k_aggr<1,1><<<dim3(2048),dim3(256),0,stream>>>(featH,alpha,src,bias1,h1H,dbn_raw,0,
                                                 vprep+1024,el,er);
  // GAT layer 2
  k_gemm<0><<<gg,dim3(256),0,stream>>>(h1H,h1H,h1H,fc2h,featH,(float*)nullptr,
                                       (float*)nullptr,(float*)nullptr,(float*)nullptr,256,256,4);
  k_alpha<<<dim3(391),dim3(256),0,stream>>>(el,er,src,alpha);
  k_aggr<2,1><<<dim3(2048),dim3(256),0,stream>>>(featH,alpha,src,bias2,h2H,dbn_raw,256,
                                                 vprep+1024,el,er);
  // GAT layer 3
  k_gemm<0><<<gg,dim3(256),0,stream>>>(h2H,h2H,h2H,fc2h,featH,(float*)nullptr,
                                       (float*)nullptr,(float*)nullptr,(float*)nullptr,256,256,4);
  k_alpha<<<dim3(391),dim3(256),0,stream>>>(el,er,src,alpha);
  k_aggr<3,0><<<dim3(2048),dim3(256),0,stream>>>(featH,alpha,src,bias2,h0H,dbn_raw,512,
                                                 vprep+1024,el,er);
  // dbn + folded cosine head
  k_dbnfin<<<dim3(3),dim3(256),0,stream>>>(dbn_raw,dbng,dbnb,dbn_ab);
  k_wfold<<<dim3(64),dim3(256),0,stream>>>(cw,dbn_ab,wfh,tvec);
  k_rnorm<<<dim3(1024),dim3(256),0,stream>>>(h1H,h2H,h0H,dbn_ab,rnorm);
  k_gemm<1><<<gg,dim3(256),0,stream>>>(h1H,h2H,h0H,wfh,(u16*)nullptr,
                                       (float*)d_out,tvec,rnorm,(float*)nullptr,256,768,12);
}